// Round 1
// 1181.487 us; speedup vs baseline: 1.1609x; 1.1609x over previous
//
#include <hip/hip_runtime.h>

#define BM 64
#define KDIM 128
#define SC 896
#define LDSS 136   // LDS row stride in ushorts (128 + 8 pad)

typedef __bf16 bf16x8 __attribute__((ext_vector_type(8)));
typedef float f32x4 __attribute__((ext_vector_type(4)));

__device__ __forceinline__ unsigned int f2bf(float f) {
  union { float f; unsigned int u; } v; v.f = f;
  unsigned int u = v.u;
  return ((u + 0x7FFFu + ((u >> 16) & 1u)) >> 16) & 0xFFFFu;
}

__device__ __forceinline__ f32x4 mfma16(uint4 a, uint4 b, f32x4 c) {
  union { uint4 u; bf16x8 v; } A, B;
  A.u = a; B.u = b;
  return __builtin_amdgcn_mfma_f32_16x16x32_bf16(A.v, B.v, c, 0, 0, 0);
}

__device__ __forceinline__ float silu_f(float x) {
  return x / (1.0f + __expf(-x));
}

// ---------------------------------------------------------------------------
// Pre-pass: fp32 weights -> bf16 MFMA B-fragments.
// COLUMN REMAP: fragment nt, col ln holds source row
//   n = J*128 + (nt>>2)*64 + ln*4 + (nt&3)
// so each lane's 8 outputs across nt are 2x4 CONTIGUOUS floats
// (cols [ln*4, ln*4+4) and [64+ln*4, 64+ln*4+4)) -> dense dwordx4 epilogue.
// K-layout unchanged: kb = kt*32 + (lane>>4)*8, 8 consecutive k per group.
// ---------------------------------------------------------------------------
__global__ void pack_kernel(const float* __restrict__ W,
                            const float* __restrict__ G,
                            const float* __restrict__ XW,
                            unsigned short* __restrict__ Wp,
                            unsigned short* __restrict__ Gp,
                            unsigned short* __restrict__ XWp) {
  int g = blockIdx.x * blockDim.x + threadIdx.x;
  const float* src;
  unsigned short* dst;
  int gg;
  if (g < 14336)       { src = W;  dst = Wp;  gg = g; }
  else if (g < 28672)  { src = G;  dst = Gp;  gg = g - 14336; }
  else                 { src = XW; dst = XWp; gg = g - 28672; }
  int lane = gg & 63;
  int kt = (gg >> 6) & 3;
  int nt = (gg >> 8) & 7;
  int J  = gg >> 11;
  int n  = J * 128 + (nt >> 2) * 64 + (lane & 15) * 4 + (nt & 3);
  int kb = kt * 32 + (lane >> 4) * 8;
  const float* s = src + n * 128 + kb;
  unsigned short* o = dst + gg * 8;
#pragma unroll
  for (int t = 0; t < 8; t++) o[t] = (unsigned short)f2bf(s[t]);
}

// ---------------------------------------------------------------------------
// o-chunk: o = attn + (t@W^T + b1) * silu(h@G^T + b2), one 128-col chunk j.
// With the remap, lane's col for fragment nt is (nt>>2)*64 + ln*4 + (nt&3).
// attn loads issued between the two GEMMs so the W-GEMM hides their latency.
// ---------------------------------------------------------------------------
__device__ __forceinline__ void compute_o(
    int j, const unsigned short* tbase, const unsigned short* hbase,
    const uint4* __restrict__ Wp, const uint4* __restrict__ Gp,
    const float* __restrict__ b1, const float* __restrict__ b2,
    const float* __restrict__ attn, int e_r0, int ln, int lane, f32x4 o[8]) {
  const f32x4 zero = {0.f, 0.f, 0.f, 0.f};
  const uint4* Gj = Gp + j * 2048 + lane;
  const uint4* Wj = Wp + j * 2048 + lane;
  // bias vectors: 2x4 contiguous floats per lane
  f32x4 bg0 = *(const f32x4*)(b2 + j * 128 + ln * 4);
  f32x4 bg1 = *(const f32x4*)(b2 + j * 128 + 64 + ln * 4);
  f32x4 bw0 = *(const f32x4*)(b1 + j * 128 + ln * 4);
  f32x4 bw1 = *(const f32x4*)(b1 + j * 128 + 64 + ln * 4);

  f32x4 g[8];
#pragma unroll
  for (int nt = 0; nt < 8; nt++) g[nt] = zero;
#pragma unroll
  for (int kt = 0; kt < 4; kt++) {
    uint4 a = *(const uint4*)(hbase + kt * 32);
#pragma unroll
    for (int nt = 0; nt < 8; nt++)
      g[nt] = mfma16(a, Gj[(nt * 4 + kt) * 64], g[nt]);
  }

  // attn prefetch: 8 dense dwordx4, in flight under the W-GEMM below
  f32x4 at0[4], at1[4];
  const float* abase = attn + j * 128 + ln * 4;
#pragma unroll
  for (int r = 0; r < 4; r++) {
    at0[r] = *(const f32x4*)(abase + (e_r0 + r) * SC);
    at1[r] = *(const f32x4*)(abase + (e_r0 + r) * SC + 64);
  }

#pragma unroll
  for (int nt = 0; nt < 8; nt++) {
    float bias = (nt < 4) ? bg0[nt] : bg1[nt - 4];
#pragma unroll
    for (int r = 0; r < 4; r++) g[nt][r] = silu_f(g[nt][r] + bias);
  }

  f32x4 acc[8];
#pragma unroll
  for (int nt = 0; nt < 8; nt++) acc[nt] = zero;
#pragma unroll
  for (int kt = 0; kt < 4; kt++) {
    uint4 a = *(const uint4*)(tbase + kt * 32);
#pragma unroll
    for (int nt = 0; nt < 8; nt++)
      acc[nt] = mfma16(a, Wj[(nt * 4 + kt) * 64], acc[nt]);
  }

#pragma unroll
  for (int nt = 0; nt < 8; nt++) {
    float bias = (nt < 4) ? bw0[nt] : bw1[nt - 4];
#pragma unroll
    for (int r = 0; r < 4; r++) {
      float at = (nt < 4) ? at0[r][nt] : at1[r][nt - 4];
      o[nt][r] = at + (acc[nt][r] + bias) * g[nt][r];
    }
  }
}

__global__ __launch_bounds__(256, 2) void gata_main(
    const float* __restrict__ attn, const float* __restrict__ t_ij,
    const float* __restrict__ h_j, const float* __restrict__ X_j,
    const float* __restrict__ rl_ij, const float* __restrict__ b1,
    const float* __restrict__ b2, const uint4* __restrict__ Wp,
    const uint4* __restrict__ Gp, const uint4* __restrict__ XWp,
    float* __restrict__ out) {
  __shared__ __align__(16) unsigned short tA[BM * LDSS];
  __shared__ __align__(16) unsigned short hA[BM * LDSS];
  __shared__ float rlS[BM * 13];

  const int tid = threadIdx.x;
  const int lane = tid & 63;
  const int wave = tid >> 6;
  const int ln = lane & 15;
  const int quad = lane >> 4;
  const int e0 = blockIdx.x * BM;

  // Stage t, h tiles to LDS as bf16 (coalesced float4 reads, uint2 LDS writes).
#pragma unroll
  for (int it = 0; it < 8; it++) {
    int f4 = tid + it * 256;           // 0..2047
    int r = f4 >> 5;                   // 0..63
    int c4 = (f4 & 31) << 2;           // 0,4,...,124
    float4 tv = *(const float4*)(t_ij + (e0 + r) * KDIM + c4);
    float4 hv = *(const float4*)(h_j + (e0 + r) * KDIM + c4);
    uint2 tw, hw;
    tw.x = f2bf(tv.x) | (f2bf(tv.y) << 16);
    tw.y = f2bf(tv.z) | (f2bf(tv.w) << 16);
    hw.x = f2bf(hv.x) | (f2bf(hv.y) << 16);
    hw.y = f2bf(hv.z) | (f2bf(hv.w) << 16);
    *(uint2*)(tA + r * LDSS + c4) = tw;
    *(uint2*)(hA + r * LDSS + c4) = hw;
  }
  // Stage rl (13 of 15 degrees used).
#pragma unroll
  for (int it = 0; it < 4; it++) {
    int idx = tid + it * 256;
    if (idx < BM * 13) {
      int r = idx / 13;
      int d = idx - r * 13;
      rlS[idx] = rl_ij[(e0 + r) * 15 + d];
    }
  }
  __syncthreads();

  const int ew = e0 + wave * 16;       // wave's first e-row
  const int e_r0 = ew + quad * 4;      // this lane's first C-row e
  const unsigned short* tbase = tA + (wave * 16 + ln) * LDSS + quad * 8;
  const unsigned short* hbase = hA + (wave * 16 + ln) * LDSS + quad * 8;
  const uint4* XWl = XWp + lane;
  const f32x4 zero = {0.f, 0.f, 0.f, 0.f};

  // Stage 0: out row 0 = silu(o_chunk0), dense dwordx4 stores
  {
    f32x4 o0[8];
    compute_o(0, tbase, hbase, Wp, Gp, b1, b2, attn, e_r0, ln, lane, o0);
#pragma unroll
    for (int r = 0; r < 4; r++) {
      f32x4 v0, v1;
#pragma unroll
      for (int q = 0; q < 4; q++) {
        v0[q] = silu_f(o0[q][r]);
        v1[q] = silu_f(o0[4 + q][r]);
      }
      float* p = out + ((e_r0 + r) * 14 + 0) * 128 + ln * 4;
      *(f32x4*)p = v0;
      *(f32x4*)(p + 64) = v1;
    }
  }

  // Stages i=0..2: out rows 1+d = o_{1+i}*rl_d + o_{4+i}*Xp_d
  const int s0s[3] = {0, 3, 8};
  const int ms[3] = {3, 5, 5};
  const float* xbase = X_j + (ew + ln) * 15 * KDIM + quad * 8;
  for (int i = 0; i < 3; i++) {
    f32x4 oA[8], oB[8];
    compute_o(1 + i, tbase, hbase, Wp, Gp, b1, b2, attn, e_r0, ln, lane, oA);
    compute_o(4 + i, tbase, hbase, Wp, Gp, b1, b2, attn, e_r0, ln, lane, oB);
    const int s0 = s0s[i];
    const int sEnd = s0 + ms[i];

    // depth-1 software pipeline on the X_j stream (largest HBM input)
    f32x4 xv[8];
#pragma unroll
    for (int kt = 0; kt < 4; kt++) {
      xv[2 * kt]     = *(const f32x4*)(xbase + s0 * KDIM + kt * 32);
      xv[2 * kt + 1] = *(const f32x4*)(xbase + s0 * KDIM + kt * 32 + 4);
    }
    for (int d = s0; d < sEnd; d++) {
      // convert current row to A-fragments
      uint4 af[4];
#pragma unroll
      for (int kt = 0; kt < 4; kt++) {
        af[kt].x = f2bf(xv[2 * kt][0])     | (f2bf(xv[2 * kt][1]) << 16);
        af[kt].y = f2bf(xv[2 * kt][2])     | (f2bf(xv[2 * kt][3]) << 16);
        af[kt].z = f2bf(xv[2 * kt + 1][0]) | (f2bf(xv[2 * kt + 1][1]) << 16);
        af[kt].w = f2bf(xv[2 * kt + 1][2]) | (f2bf(xv[2 * kt + 1][3]) << 16);
      }
      // prefetch next row (clamped on last iter -> L1 hit, harmless)
      int dn = (d + 1 < sEnd) ? d + 1 : d;
      f32x4 xn[8];
#pragma unroll
      for (int kt = 0; kt < 4; kt++) {
        xn[2 * kt]     = *(const f32x4*)(xbase + dn * KDIM + kt * 32);
        xn[2 * kt + 1] = *(const f32x4*)(xbase + dn * KDIM + kt * 32 + 4);
      }
      // xp = X_row @ XW^T
      f32x4 xp[8];
#pragma unroll
      for (int nt = 0; nt < 8; nt++) xp[nt] = zero;
#pragma unroll
      for (int kt = 0; kt < 4; kt++) {
#pragma unroll
        for (int nt = 0; nt < 8; nt++)
          xp[nt] = mfma16(af[kt], XWl[(nt * 4 + kt) * 64], xp[nt]);
      }
      // epilogue: dense dwordx4 stores
#pragma unroll
      for (int r = 0; r < 4; r++) {
        float rl = rlS[(wave * 16 + quad * 4 + r) * 13 + d];
        f32x4 v0, v1;
#pragma unroll
        for (int q = 0; q < 4; q++) {
          v0[q] = oA[q][r] * rl + oB[q][r] * xp[q][r];
          v1[q] = oA[4 + q][r] * rl + oB[4 + q][r] * xp[4 + q][r];
        }
        float* p = out + ((e_r0 + r) * 14 + 1 + d) * 128 + ln * 4;
        *(f32x4*)p = v0;
        *(f32x4*)(p + 64) = v1;
      }
#pragma unroll
      for (int k = 0; k < 8; k++) xv[k] = xn[k];
    }
  }
}

extern "C" void kernel_launch(void* const* d_in, const int* in_sizes, int n_in,
                              void* d_out, int out_size, void* d_ws, size_t ws_size,
                              hipStream_t stream) {
  const float* attn = (const float*)d_in[0];
  const float* t_ij = (const float*)d_in[1];
  const float* h_j  = (const float*)d_in[2];
  const float* X_j  = (const float*)d_in[3];
  const float* rl   = (const float*)d_in[4];
  const float* W    = (const float*)d_in[5];
  const float* b1   = (const float*)d_in[6];
  const float* G    = (const float*)d_in[7];
  const float* b2   = (const float*)d_in[8];
  const float* XW   = (const float*)d_in[9];

  unsigned short* Wp  = (unsigned short*)d_ws;       // 14336*8 ushorts
  unsigned short* Gp  = Wp + 14336 * 8;              // 14336*8 ushorts
  unsigned short* XWp = Gp + 14336 * 8;              // 2048*8 ushorts

  const int E = in_sizes[1] / KDIM;                  // 65536
  pack_kernel<<<120, 256, 0, stream>>>(W, G, XW, Wp, Gp, XWp);
  gata_main<<<E / BM, 256, 0, stream>>>(attn, t_ij, h_j, X_j, rl, b1, b2,
                                        (const uint4*)Wp, (const uint4*)Gp,
                                        (const uint4*)XWp, (float*)d_out);
}